// Round 7
// baseline (35.424 us; speedup 1.0000x reference)
//
#include <hip/hip_runtime.h>

#define GDIM 104
#define GG (GDIM * GDIM)          // 10816
#define NA 3
#define NB 128
#define NCPT 2                    // cells per thread
#define NBLK 2704                 // NB*GG / (256*NCPT)
#define IMGF 832.0f
#define EPSF 1e-9f
#define PI_F 3.14159265358979323846f
#define INV_G (1.0f / 104.0f)

typedef float f32x4 __attribute__((ext_vector_type(4)));

// 1-instruction reciprocal (v_rcp_f32, rel err ~2^-22 — fine at threshold 348)
__device__ __forceinline__ float rcp_(float x) { return __builtin_amdgcn_rcpf(x); }

__device__ __forceinline__ float sigmoid_fast(float z) {
    return rcp_(1.0f + __expf(-z));
}

// acos minimax (Abramowitz-Stegun 4.4.45), |err| < 7e-5 rad
__device__ __forceinline__ float acos_fast(float x) {
    float ax = fabsf(x);
    float t = sqrtf(fmaxf(1.0f - ax, 0.0f));
    float p = fmaf(-0.0187293f, ax, 0.0742610f);
    p = fmaf(p, ax, -0.2121144f);
    p = fmaf(p, ax, 1.5707288f);
    float r = t * p;
    return (x < 0.0f) ? (PI_F - r) : r;
}

// 2 cells/thread, lane-contiguous loads AND stores; 2704 blocks -> 42 waves/CU
// launched (32 resident) for max bytes-in-flight.
__global__ __launch_bounds__(256) void det_main(const float* __restrict__ x,
                                                const float* __restrict__ tg,
                                                f32x4* __restrict__ out4,
                                                float* __restrict__ ws) {
    const float PR[NA] = {20.0f / 8.0f, 50.0f / 8.0f, 110.0f / 8.0f};   // ANCHORS/stride
    const float AR[NA] = {20.0f / IMGF, 50.0f / IMGF, 110.0f / IMGF};   // ANCHORS/IMAGE_SIZE

    int base = blockIdx.x * (256 * NCPT) + threadIdx.x;

    // ---- issue loads up front (lane-contiguous scalar loads) ----
    int bb[NCPT], rr[NCPT];
    float vt[NCPT][4];     // targets [c][plane]
    float vp[NCPT][12];    // x       [c][plane]
#pragma unroll
    for (int c = 0; c < NCPT; ++c) {
        int gc = base + c * 256;
        int b = gc / GG;
        int r = gc - b * GG;
        bb[c] = b; rr[c] = r;
        const float* tb = tg + (size_t)b * (4 * GG) + r;
#pragma unroll
        for (int p = 0; p < 4; ++p) vt[c][p] = tb[(size_t)p * GG];
        const float* xb = x + (size_t)b * (12 * GG) + r;
#pragma unroll
        for (int p = 0; p < 12; ++p) vp[c][p] = xb[(size_t)p * GG];
    }

    float l_fl = 0.0f, l_di = 0.0f;
    int   l_n  = 0;

#pragma unroll
    for (int c = 0; c < NCPT; ++c) {
        int b = bb[c], r = rr[c];
        int i = r / GDIM;
        int j = r - i * GDIM;
        float fi = (float)i, fj = (float)j;

        float tx  = vt[c][0];
        float ty  = vt[c][1];
        float trr = vt[c][2];
        float cf  = vt[c][3];
        float tgx = (fj + tx) * INV_G;
        float tgy = (fi + ty) * INV_G;

        // best anchor = argmax riou (first-max tie rule via strict >)
        int best = 0;
        float bestv = -1.0f;
#pragma unroll
        for (int a = 0; a < NA; ++a) {
            float q = fminf(trr, AR[a]) * rcp_(fmaxf(trr, AR[a]) + EPSF);
            float ri = q * q;
            if (ri > bestv) { bestv = ri; best = a; }
        }
        bool pos = (cf > 0.5f);

        size_t obase = (size_t)b * (NA * GG) + r;
        float sbx = 0.0f, sby = 0.0f, sbr = 0.0f;
#pragma unroll
        for (int a = 0; a < NA; ++a) {
            float p0 = vp[c][a * 4 + 0];
            float p1 = vp[c][a * 4 + 1];
            float p2 = vp[c][a * 4 + 2];
            float p3 = vp[c][a * 4 + 3];

            float sx = sigmoid_fast(p0);
            float sy = sigmoid_fast(p1);
            float br = PR[a] * __expf(p2) * INV_G;

            float e   = __expf(-p3);
            float pc  = rcp_(1.0f + e);
            float l1e = __logf(1.0f + e);     // = -log_sigmoid(p3)

            f32x4 o;
            o.x = (sx + fj) * 8.0f;
            o.y = (sy + fi) * 8.0f;
            o.z = br * IMGF;
            o.w = pc;
            // lane-contiguous 16B non-temporal stores (output never re-read)
            __builtin_nontemporal_store(o, &out4[obase + (size_t)a * GG]);

            bool obj = pos && (a == best);
            float u = 1.0f - pc;
            l_fl += obj ? 0.25f * u * u * l1e : 0.75f * pc * pc * (p3 + l1e);

            if (a == best) { sbx = (sx + fj) * INV_G; sby = (sy + fi) * INV_G; sbr = br; }
        }

        if (pos) {
            l_n += 1;
            float dx = sbx - tgx, dy = sby - tgy;
            float d2 = dx * dx + dy * dy;
            float d  = sqrtf(d2 + EPSF);
            float r1 = sbr, r2 = trr;
            float rmin = fminf(r1, r2), rmax = fmaxf(r1, r2);
            float a1 = (d2 + r1 * r1 - r2 * r2) * rcp_(2.0f * d * r1 + EPSF);
            a1 = fminf(fmaxf(a1, -1.0f), 1.0f);
            float a2 = (d2 + r2 * r2 - r1 * r1) * rcp_(2.0f * d * r2 + EPSF);
            a2 = fminf(fmaxf(a2, -1.0f), 1.0f);
            float tt = (-d + r1 + r2) * (d + r1 - r2) * (d - r1 + r2) * (d + r1 + r2);
            tt = fmaxf(tt, 0.0f);
            float lens = r1 * r1 * acos_fast(a1) + r2 * r2 * acos_fast(a2) - 0.5f * sqrtf(tt);
            float inter = (d >= r1 + r2) ? 0.0f
                         : ((d <= rmax - rmin) ? PI_F * rmin * rmin : lens);
            float uni = PI_F * (r1 * r1 + r2 * r2) - inter;
            float iou = inter * rcp_(uni + EPSF);
            float s = d + r1 + r2;
            float pen = d2 * rcp_(s * s + EPSF);
            l_di += 1.0f - iou + pen;
        }
    }

    // wave64 reduce
    float l_nf = (float)l_n;
#pragma unroll
    for (int off = 32; off > 0; off >>= 1) {
        l_di += __shfl_down(l_di, off);
        l_fl += __shfl_down(l_fl, off);
        l_nf += __shfl_down(l_nf, off);
    }

    __shared__ float sdiou[4], sfl[4], sn[4];
    int wid  = threadIdx.x >> 6;
    int lane = threadIdx.x & 63;
    if (lane == 0) { sdiou[wid] = l_di; sfl[wid] = l_fl; sn[wid] = l_nf; }
    __syncthreads();
    if (threadIdx.x == 0) {
        float ds = 0.0f, fs = 0.0f, ns = 0.0f;
#pragma unroll
        for (int w = 0; w < 4; ++w) { ds += sdiou[w]; fs += sfl[w]; ns += sn[w]; }
        ws[blockIdx.x]            = ds;
        ws[NBLK + blockIdx.x]     = fs;
        ws[2 * NBLK + blockIdx.x] = ns;
    }
}

__global__ __launch_bounds__(256) void det_finalize(const float* __restrict__ ws,
                                                    float* __restrict__ out_scalar) {
    float ds = 0.0f, fs = 0.0f, ns = 0.0f;
    for (int k = threadIdx.x; k < NBLK; k += 256) {
        ds += ws[k];
        fs += ws[NBLK + k];
        ns += ws[2 * NBLK + k];
    }
#pragma unroll
    for (int off = 32; off > 0; off >>= 1) {
        ds += __shfl_down(ds, off);
        fs += __shfl_down(fs, off);
        ns += __shfl_down(ns, off);
    }
    __shared__ float s0[4], s1[4], s2[4];
    int wid  = threadIdx.x >> 6;
    int lane = threadIdx.x & 63;
    if (lane == 0) { s0[wid] = ds; s1[wid] = fs; s2[wid] = ns; }
    __syncthreads();
    if (threadIdx.x == 0) {
        float D = 0.0f, F = 0.0f, N = 0.0f;
#pragma unroll
        for (int w = 0; w < 4; ++w) { D += s0[w]; F += s1[w]; N += s2[w]; }
        double n = (N < 1.0f) ? 1.0 : (double)N;
        out_scalar[0] = (float)((double)D / n + (double)F / (double)((size_t)NB * NA * GG));
    }
}

extern "C" void kernel_launch(void* const* d_in, const int* in_sizes, int n_in,
                              void* d_out, int out_size, void* d_ws, size_t ws_size,
                              hipStream_t stream) {
    const float* x  = (const float*)d_in[0];
    const float* tg = (const float*)d_in[1];
    float* out = (float*)d_out;
    float* ws  = (float*)d_ws;

    det_main<<<NBLK, 256, 0, stream>>>(x, tg, (f32x4*)out, ws);
    det_finalize<<<1, 256, 0, stream>>>(ws, out + (size_t)NB * NA * GG * 4);
}

// Round 8
// 34.887 us; speedup vs baseline: 1.0154x; 1.0154x over previous
//
#include <hip/hip_runtime.h>

#define GDIM 104
#define GG (GDIM * GDIM)          // 10816
#define GG4 (GG / 4)              // 2704
#define NA 3
#define NB 128
#define NBLK 1352                 // NB*GG / 1024
#define IMGF 832.0f
#define EPSF 1e-9f
#define PI_F 3.14159265358979323846f
#define INV_G (1.0f / 104.0f)

typedef float f32x4 __attribute__((ext_vector_type(4)));

// 1-instruction reciprocal (v_rcp_f32, rel err ~2^-22 — fine at threshold 348)
__device__ __forceinline__ float rcp_(float x) { return __builtin_amdgcn_rcpf(x); }

__device__ __forceinline__ float sigmoid_fast(float z) {
    return rcp_(1.0f + __expf(-z));
}

// acos minimax (Abramowitz-Stegun 4.4.45), |err| < 7e-5 rad
__device__ __forceinline__ float acos_fast(float x) {
    float ax = fabsf(x);
    float t = sqrtf(fmaxf(1.0f - ax, 0.0f));
    float p = fmaf(-0.0187293f, ax, 0.0742610f);
    p = fmaf(p, ax, -0.2121144f);
    p = fmaf(p, ax, 1.5707288f);
    float r = t * p;
    return (x < 0.0f) ? (PI_F - r) : r;
}

// LDS slot swizzle: XOR low-2 bits with bits[5:4]; involution, write side <=2-way
// bank conflict (free), read side conflict-free.
__device__ __forceinline__ int swz(int m) { return m ^ ((m >> 4) & 3); }

// Thread owns 4 consecutive cells (one float4 per plane): 16 dwordx4 loads.
// Stores go through a wave-private 4KB LDS transpose so each global store is a
// lane-contiguous float4 (ideal WRITE_SIZE, unlike R3's strided stores).
__global__ __launch_bounds__(256) void det_main(const f32x4* __restrict__ x4,
                                                const f32x4* __restrict__ tg4,
                                                f32x4* __restrict__ out4,
                                                float* __restrict__ ws) {
    __shared__ f32x4 lds[1024];   // 16 KB: 4 waves x 256 slots (wave-private)

    const float PR[NA] = {20.0f / 8.0f, 50.0f / 8.0f, 110.0f / 8.0f};
    const float AR[NA] = {20.0f / IMGF, 50.0f / IMGF, 110.0f / IMGF};

    int tid  = threadIdx.x;
    int lane = tid & 63;
    int wid  = tid >> 6;

    int gq = blockIdx.x * 256 + tid;          // float4-quad id (4 cells)
    int b  = gq / GG4;
    int rq = gq - b * GG4;
    int r0 = rq << 2;                          // first cell in row-space
    int i  = r0 / GDIM;
    int j0 = r0 - i * GDIM;                    // divisible by 4
    float fi = (float)i;

    // ---- all loads up front: 4 target f4 + 12 x f4 ----
    const f32x4* tb = tg4 + (size_t)b * (4 * GG4) + rq;
    f32x4 vtx = tb[0 * GG4];
    f32x4 vty = tb[1 * GG4];
    f32x4 vtr = tb[2 * GG4];
    f32x4 vcf = tb[3 * GG4];

    const f32x4* xb = x4 + (size_t)b * (12 * GG4) + rq;
    f32x4 P[12];
#pragma unroll
    for (int p = 0; p < 12; ++p) P[p] = xb[(size_t)p * GG4];

    // store-side base index per store-instruction k (cell = 64k + lane of this wave)
    int cbase[4];
#pragma unroll
    for (int k = 0; k < 4; ++k) {
        int gcell = blockIdx.x * 1024 + wid * 256 + 64 * k + lane;
        int bS = gcell / GG;
        int rS = gcell - bS * GG;
        cbase[k] = bS * (NA * GG) + rS;
    }

    // per-cell target decode + best anchor (first-max tie rule via strict >)
    float tgx[4], tgy[4];
    bool  pos[4];
    int   best[4];
#pragma unroll
    for (int c = 0; c < 4; ++c) {
        float tr = vtr[c];
        float fj = (float)(j0 + c);
        tgx[c] = (fj + vtx[c]) * INV_G;
        tgy[c] = (fi + vty[c]) * INV_G;
        pos[c] = vcf[c] > 0.5f;
        int bs = 0; float bv = -1.0f;
#pragma unroll
        for (int a = 0; a < NA; ++a) {
            float q = fminf(tr, AR[a]) * rcp_(fmaxf(tr, AR[a]) + EPSF);
            float ri = q * q;
            if (ri > bv) { bv = ri; bs = a; }
        }
        best[c] = bs;
    }

    float l_fl = 0.0f, l_di = 0.0f;
    int   l_n  = 0;
    float sbx[4] = {0}, sby[4] = {0}, sbr[4] = {0};

#pragma unroll
    for (int a = 0; a < NA; ++a) {
#pragma unroll
        for (int c = 0; c < 4; ++c) {
            float p0 = P[a * 4 + 0][c];
            float p1 = P[a * 4 + 1][c];
            float p2 = P[a * 4 + 2][c];
            float p3 = P[a * 4 + 3][c];
            float fj = (float)(j0 + c);

            float sx = sigmoid_fast(p0);
            float sy = sigmoid_fast(p1);
            float br = PR[a] * __expf(p2) * INV_G;

            float e   = __expf(-p3);
            float pc  = rcp_(1.0f + e);
            float l1e = __logf(1.0f + e);     // = -log_sigmoid(p3)

            f32x4 o;
            o.x = (sx + fj) * 8.0f;
            o.y = (sy + fi) * 8.0f;
            o.z = br * IMGF;
            o.w = pc;
            int m = 4 * lane + c;
            lds[wid * 256 + swz(m)] = o;

            bool obj = pos[c] && (a == best[c]);
            float u = 1.0f - pc;
            l_fl += obj ? 0.25f * u * u * l1e : 0.75f * pc * pc * (p3 + l1e);

            if (a == best[c]) { sbx[c] = (sx + fj) * INV_G; sby[c] = (sy + fi) * INV_G; sbr[c] = br; }
        }
        // intra-wave exchange: drain ds_writes, then lane-contiguous f4 stores
        asm volatile("s_waitcnt lgkmcnt(0)" ::: "memory");
#pragma unroll
        for (int k = 0; k < 4; ++k) {
            int m = 64 * k + lane;
            f32x4 o = lds[wid * 256 + swz(m)];
            __builtin_nontemporal_store(o, &out4[(size_t)cbase[k] + (size_t)a * GG]);
        }
        asm volatile("s_waitcnt lgkmcnt(0)" ::: "memory");
    }

    // DIoU once per positive cell (best anchor's box)
#pragma unroll
    for (int c = 0; c < 4; ++c) {
        if (pos[c]) {
            l_n += 1;
            float dx = sbx[c] - tgx[c], dy = sby[c] - tgy[c];
            float d2 = dx * dx + dy * dy;
            float d  = sqrtf(d2 + EPSF);
            float r1 = sbr[c], r2 = vtr[c];
            float rmin = fminf(r1, r2), rmax = fmaxf(r1, r2);
            float a1 = (d2 + r1 * r1 - r2 * r2) * rcp_(2.0f * d * r1 + EPSF);
            a1 = fminf(fmaxf(a1, -1.0f), 1.0f);
            float a2 = (d2 + r2 * r2 - r1 * r1) * rcp_(2.0f * d * r2 + EPSF);
            a2 = fminf(fmaxf(a2, -1.0f), 1.0f);
            float tt = (-d + r1 + r2) * (d + r1 - r2) * (d - r1 + r2) * (d + r1 + r2);
            tt = fmaxf(tt, 0.0f);
            float lens = r1 * r1 * acos_fast(a1) + r2 * r2 * acos_fast(a2) - 0.5f * sqrtf(tt);
            float inter = (d >= r1 + r2) ? 0.0f
                         : ((d <= rmax - rmin) ? PI_F * rmin * rmin : lens);
            float uni = PI_F * (r1 * r1 + r2 * r2) - inter;
            float iou = inter * rcp_(uni + EPSF);
            float s = d + r1 + r2;
            float pen = d2 * rcp_(s * s + EPSF);
            l_di += 1.0f - iou + pen;
        }
    }

    // wave64 reduce
    float l_nf = (float)l_n;
#pragma unroll
    for (int off = 32; off > 0; off >>= 1) {
        l_di += __shfl_down(l_di, off);
        l_fl += __shfl_down(l_fl, off);
        l_nf += __shfl_down(l_nf, off);
    }

    __shared__ float sdiou[4], sfl[4], snn[4];
    if (lane == 0) { sdiou[wid] = l_di; sfl[wid] = l_fl; snn[wid] = l_nf; }
    __syncthreads();
    if (tid == 0) {
        float ds = 0.0f, fs = 0.0f, ns = 0.0f;
#pragma unroll
        for (int w = 0; w < 4; ++w) { ds += sdiou[w]; fs += sfl[w]; ns += snn[w]; }
        ws[blockIdx.x]            = ds;
        ws[NBLK + blockIdx.x]     = fs;
        ws[2 * NBLK + blockIdx.x] = ns;
    }
}

__global__ __launch_bounds__(256) void det_finalize(const float* __restrict__ ws,
                                                    float* __restrict__ out_scalar) {
    float ds = 0.0f, fs = 0.0f, ns = 0.0f;
    for (int k = threadIdx.x; k < NBLK; k += 256) {
        ds += ws[k];
        fs += ws[NBLK + k];
        ns += ws[2 * NBLK + k];
    }
#pragma unroll
    for (int off = 32; off > 0; off >>= 1) {
        ds += __shfl_down(ds, off);
        fs += __shfl_down(fs, off);
        ns += __shfl_down(ns, off);
    }
    __shared__ float s0[4], s1[4], s2[4];
    int wid  = threadIdx.x >> 6;
    int lane = threadIdx.x & 63;
    if (lane == 0) { s0[wid] = ds; s1[wid] = fs; s2[wid] = ns; }
    __syncthreads();
    if (threadIdx.x == 0) {
        float D = 0.0f, F = 0.0f, N = 0.0f;
#pragma unroll
        for (int w = 0; w < 4; ++w) { D += s0[w]; F += s1[w]; N += s2[w]; }
        double n = (N < 1.0f) ? 1.0 : (double)N;
        out_scalar[0] = (float)((double)D / n + (double)F / (double)((size_t)NB * NA * GG));
    }
}

extern "C" void kernel_launch(void* const* d_in, const int* in_sizes, int n_in,
                              void* d_out, int out_size, void* d_ws, size_t ws_size,
                              hipStream_t stream) {
    const f32x4* x4  = (const f32x4*)d_in[0];
    const f32x4* tg4 = (const f32x4*)d_in[1];
    float* out = (float*)d_out;
    float* ws  = (float*)d_ws;

    det_main<<<NBLK, 256, 0, stream>>>(x4, tg4, (f32x4*)out, ws);
    det_finalize<<<1, 256, 0, stream>>>(ws, out + (size_t)NB * NA * GG * 4);
}